// Round 1
// baseline (118.912 us; speedup 1.0000x reference)
//
#include <hip/hip_runtime.h>
#include <stdint.h>

// Problem constants: B=4, QL=256, CL=512, XD=ED=DIM=128, YD=16
#define Bc   4
#define QLc  256
#define CLc  512
#define Dc   128
#define YDc  16
#define NROW (Bc * QLc)     // 1024 (b,q) rows
#define RPB  4              // rows per block
#define TPB  512            // threads per block (8 waves)

// ---------------- Threefry-2x32, 20 rounds (exact JAX semantics) -------------
__device__ __forceinline__ uint32_t rotl32(uint32_t x, int d) {
  return (x << d) | (x >> (32 - d));
}

__device__ __forceinline__ void tf2x32(uint32_t k0, uint32_t k1, uint32_t x0,
                                       uint32_t x1, uint32_t& o0, uint32_t& o1) {
  const uint32_t k2 = k0 ^ k1 ^ 0x1BD11BDAu;
  uint32_t v0 = x0 + k0, v1 = x1 + k1;
  v0 += v1; v1 = rotl32(v1, 13); v1 ^= v0;
  v0 += v1; v1 = rotl32(v1, 15); v1 ^= v0;
  v0 += v1; v1 = rotl32(v1, 26); v1 ^= v0;
  v0 += v1; v1 = rotl32(v1, 6);  v1 ^= v0;
  v0 += k1; v1 += k2 + 1u;
  v0 += v1; v1 = rotl32(v1, 17); v1 ^= v0;
  v0 += v1; v1 = rotl32(v1, 29); v1 ^= v0;
  v0 += v1; v1 = rotl32(v1, 16); v1 ^= v0;
  v0 += v1; v1 = rotl32(v1, 24); v1 ^= v0;
  v0 += k2; v1 += k0 + 2u;
  v0 += v1; v1 = rotl32(v1, 13); v1 ^= v0;
  v0 += v1; v1 = rotl32(v1, 15); v1 ^= v0;
  v0 += v1; v1 = rotl32(v1, 26); v1 ^= v0;
  v0 += v1; v1 = rotl32(v1, 6);  v1 ^= v0;
  v0 += k0; v1 += k1 + 3u;
  v0 += v1; v1 = rotl32(v1, 17); v1 ^= v0;
  v0 += v1; v1 = rotl32(v1, 29); v1 ^= v0;
  v0 += v1; v1 = rotl32(v1, 16); v1 ^= v0;
  v0 += v1; v1 = rotl32(v1, 24); v1 ^= v0;
  v0 += k1; v1 += k2 + 4u;
  v0 += v1; v1 = rotl32(v1, 13); v1 ^= v0;
  v0 += v1; v1 = rotl32(v1, 15); v1 ^= v0;
  v0 += v1; v1 = rotl32(v1, 26); v1 ^= v0;
  v0 += v1; v1 = rotl32(v1, 6);  v1 ^= v0;
  v0 += k2; v1 += k0 + 5u;
  o0 = v0; o1 = v1;
}

// jax.random.key(1) -> data (0,1). Partitionable split: keys[i] = tf(key,(0,i)).
__device__ __forceinline__ void subkeys(uint32_t& ck0, uint32_t& ck1,
                                        uint32_t& ek0, uint32_t& ek1) {
  tf2x32(0u, 1u, 0u, 0u, ck0, ck1);   // kcat
  tf2x32(0u, 1u, 0u, 1u, ek0, ek1);   // keps
}

__device__ __forceinline__ uint32_t rbits(uint32_t k0, uint32_t k1, uint32_t i) {
  uint32_t o0, o1;
  tf2x32(k0, k1, 0u, i, o0, o1);
  return o0 ^ o1;
}

// JAX uniform [0,1): ((bits>>9)|0x3f800000) bitcast - 1.0
__device__ __forceinline__ float bits_to_unit(uint32_t bits) {
  return __uint_as_float((bits >> 9) | 0x3f800000u) - 1.0f;
}

// Giles single-precision erfinv (validated: absmax 0.0 end-to-end)
__device__ __forceinline__ float erfinv_f(float x) {
  float w = -logf((1.0f - x) * (1.0f + x));
  float p;
  if (w < 5.0f) {
    w -= 2.5f;
    p = 2.81022636e-08f;
    p = fmaf(p, w, 3.43273939e-07f);
    p = fmaf(p, w, -3.5233877e-06f);
    p = fmaf(p, w, -4.39150654e-06f);
    p = fmaf(p, w, 0.00021858087f);
    p = fmaf(p, w, -0.00125372503f);
    p = fmaf(p, w, -0.00417768164f);
    p = fmaf(p, w, 0.246640727f);
    p = fmaf(p, w, 1.50140941f);
  } else {
    w = sqrtf(w) - 3.0f;
    p = -0.000200214257f;
    p = fmaf(p, w, 0.000100950558f);
    p = fmaf(p, w, 0.00134934322f);
    p = fmaf(p, w, -0.00367342844f);
    p = fmaf(p, w, 0.00573950773f);
    p = fmaf(p, w, -0.0076224613f);
    p = fmaf(p, w, 0.00943887047f);
    p = fmaf(p, w, 1.00167406f);
    p = fmaf(p, w, 2.83297682f);
  }
  return p * x;
}

// -----------------------------------------------------------------------------
// 256 blocks x 512 threads, 4 (b,q) rows per block (halves L2 weight traffic
// vs 2-row blocks at the same 8 waves/CU occupancy).
// Per row: gumbel-argmax(512) via wave shuffles -> idx; qp = q@W1q (overlapping
// the f[idx] gather latency); fp = f[idx]@W1f; h1; h2; out; sample.
// eps threefry is data-independent -> precomputed on wave 0 at kernel start.
// 5 __syncthreads total (was 13). All fmaf chains keep the exact original
// operation order -> bit-identical output (absmax 0.0).
// -----------------------------------------------------------------------------
__global__ __launch_bounds__(TPB) void k_fused(
    const float* __restrict__ q, const float* __restrict__ f,
    const float* __restrict__ logits, const float* __restrict__ W1q,
    const float* __restrict__ W1f, const float* __restrict__ b1,
    const float* __restrict__ W2, const float* __restrict__ b2,
    const float* __restrict__ Wout, const float* __restrict__ bout,
    float* __restrict__ out) {
  const int tid = threadIdx.x;
  const int r   = tid >> 7;            // 0..3 : which row of the quad
  const int l   = tid & 127;           // 0..127 : lane within row
  const int row = blockIdx.x * RPB + r;
  const int b   = row >> 8;            // QL = 256

  __shared__ __align__(16) float sxq[RPB][Dc];   // staged q rows
  __shared__ __align__(16) float sxf[RPB][Dc];   // staged f[idx] rows
  __shared__ __align__(16) float sh1[RPB][Dc];   // hidden 1
  __shared__ __align__(16) float sh2[RPB][Dc];   // hidden 2
  __shared__ float spart[RPB][4][32];            // split-K partials for Wout
  __shared__ float swv[8];                       // per-wave argmax candidates
  __shared__ int   swi[8];
  __shared__ float seps[64];                     // precomputed eps (4 rows x 16)

  // Early-issue the q element this thread owns.
  const float qv = q[row * Dc + l];

  uint32_t ck0, ck1, ek0, ek1;
  subkeys(ck0, ck1, ek0, ek1);       // constant-folds at compile time

  // ---- 0. eps precompute (data-independent), one full wave, no divergence --
  if (tid < 64) {
    const int rr = tid >> 4, y = tid & 15;
    const int orow = blockIdx.x * RPB + rr;
    const uint32_t i = (uint32_t)(orow * YDc + y);   // row-major (b,q,y)
    const uint32_t bits = rbits(ek0, ek1, i);
    const float fl = bits_to_unit(bits);
    const float lo = -0.999999940395355224609375f;   // nextafter(-1,0)
    const float prod = __fmul_rn(fl, 2.0f);
    const float u = fmaxf(lo, __fadd_rn(prod, lo));
    seps[tid] = 1.4142135623730951f * erfinv_f(u);
  }

  sxq[r][l] = qv;

  // ---- 1. gumbel-argmax over this row's 512 logits (first-max ties) --------
  float lgv[4];
#pragma unroll
  for (int j = 0; j < 4; ++j)
    lgv[j] = logits[(uint32_t)(row * CLc + (l + j * 128))];

  float best = -3.4e38f;
  int bi = 1 << 30;
#pragma unroll
  for (int j = 0; j < 4; ++j) {
    const int c = l + j * 128;
    const uint32_t i = (uint32_t)(row * CLc + c);    // row-major (b,q,c)
    const uint32_t bits = rbits(ck0, ck1, i);
    const float fl = bits_to_unit(bits);
    const float u = fmaxf(1.17549435e-38f, fl);      // JAX minval=tiny
    const float g = -logf(-logf(u));                 // gumbel
    const float val = g + lgv[j];
    if (val > best || (val == best && c < bi)) { best = val; bi = c; }
  }
  // intra-wave reduce (total order: larger val, then smaller idx — assoc.)
#pragma unroll
  for (int s = 1; s < 64; s <<= 1) {
    const float ov = __shfl_xor(best, s, 64);
    const int   oi = __shfl_xor(bi, s, 64);
    if (ov > best || (ov == best && oi < bi)) { best = ov; bi = oi; }
  }
  if ((tid & 63) == 0) { swv[tid >> 6] = best; swi[tid >> 6] = bi; }
  __syncthreads();                                   // B1: sxq + candidates

  // resolve per-row winner (row r spans waves 2r, 2r+1)
  int csel;
  {
    const float v0 = swv[2 * r], v1 = swv[2 * r + 1];
    const int   i0 = swi[2 * r], i1 = swi[2 * r + 1];
    csel = (v1 > v0 || (v1 == v0 && i1 < i0)) ? i1 : i0;
  }
  // issue the selected-f-row gather now; qp matmul below hides its latency
  const float fv = f[(b * CLc + csel) * Dc + l];

  // ---- 2. qp = q_row @ W1q (identical fmaf order to before) ---------------
  float acc1 = 0.0f;
  {
    const float4* xp = (const float4*)sxq[r];
#pragma unroll
    for (int h4 = 0; h4 < 32; ++h4) {
      const float4 xv = xp[h4];
      const int h = h4 * 4;
      acc1 = fmaf(xv.x, W1q[(h + 0) * Dc + l], acc1);
      acc1 = fmaf(xv.y, W1q[(h + 1) * Dc + l], acc1);
      acc1 = fmaf(xv.z, W1q[(h + 2) * Dc + l], acc1);
      acc1 = fmaf(xv.w, W1q[(h + 3) * Dc + l], acc1);
    }
  }

  sxf[r][l] = fv;
  __syncthreads();                                   // B2: sxf published

  // ---- 3. fp = f_embed[b, idx] @ W1f ---------------------------------------
  float accf = 0.0f;
  {
    const float4* xp = (const float4*)sxf[r];
#pragma unroll
    for (int h4 = 0; h4 < 32; ++h4) {
      const float4 xv = xp[h4];
      const int h = h4 * 4;
      accf = fmaf(xv.x, W1f[(h + 0) * Dc + l], accf);
      accf = fmaf(xv.y, W1f[(h + 1) * Dc + l], accf);
      accf = fmaf(xv.z, W1f[(h + 2) * Dc + l], accf);
      accf = fmaf(xv.w, W1f[(h + 3) * Dc + l], accf);
    }
  }

  // ---- 4. h1 = relu(qp + fp + b1) ------------------------------------------
  sh1[r][l] = fmaxf(acc1 + accf + b1[l], 0.0f);
  __syncthreads();                                   // B3: sh1 published

  // ---- 5. h2 = relu(h1 @ W2 + b2) ------------------------------------------
  float acc2 = b2[l];
  {
    const float4* xp = (const float4*)sh1[r];
#pragma unroll
    for (int h4 = 0; h4 < 32; ++h4) {
      const float4 xv = xp[h4];
      const int h = h4 * 4;
      acc2 = fmaf(xv.x, W2[(h + 0) * Dc + l], acc2);
      acc2 = fmaf(xv.y, W2[(h + 1) * Dc + l], acc2);
      acc2 = fmaf(xv.z, W2[(h + 2) * Dc + l], acc2);
      acc2 = fmaf(xv.w, W2[(h + 3) * Dc + l], acc2);
    }
  }
  sh2[r][l] = fmaxf(acc2, 0.0f);                     // separate buffer: no WAR
  __syncthreads();                                   // B4: sh2 published

  // ---- 6. out = h2 @ Wout + bout (32 cols/row, split-K by 4 groups of 32) --
  {
    const int k  = tid & 31;
    const int rr = (tid >> 5) & 3;
    const int g  = tid >> 7;                         // 0..3
    float p = 0.0f;
#pragma unroll
    for (int hh = 0; hh < 32; ++hh) {
      const int h = g * 32 + hh;
      p = fmaf(sh2[rr][h], Wout[h * 32 + k], p);
    }
    spart[rr][g][k] = p;
  }
  __syncthreads();                                   // B5: spart published

  // ---- 7. combine + sample, barrier-free tail (waves 0-1 only) -------------
  if (tid < 128) {
    const int rr = tid >> 5, k = tid & 31;           // rows 0..3, cols 0..31
    const int orow = blockIdx.x * RPB + rr;
    const float ov = bout[k] + spart[rr][0][k] + spart[rr][1][k] +
                     spart[rr][2][k] + spart[rr][3][k];
    // in-wave exchange: lane with col y grabs col 16+y (the 's' half)
    const float sv_ = __shfl(ov, (tid & 63) + 16, 64);
    if (k < 16) {
      const float mu = ov;
      const float sm = fmaxf(-15.0f, sv_);
      const float sigma = fmaxf(sm, 0.0f) + log1pf(expf(-fabsf(sm)));
      out[orow * YDc + k] = mu + sigma * seps[rr * 16 + k];
    }
  }
}

// -----------------------------------------------------------------------------
extern "C" void kernel_launch(void* const* d_in, const int* in_sizes, int n_in,
                              void* d_out, int out_size, void* d_ws, size_t ws_size,
                              hipStream_t stream) {
  const float* q      = (const float*)d_in[0];
  const float* f      = (const float*)d_in[1];
  const float* logits = (const float*)d_in[2];
  const float* W1q    = (const float*)d_in[3];
  const float* W1f    = (const float*)d_in[4];
  const float* b1     = (const float*)d_in[5];
  const float* W2     = (const float*)d_in[6];
  const float* b2     = (const float*)d_in[7];
  const float* Wout   = (const float*)d_in[8];
  const float* bout   = (const float*)d_in[9];
  float* out = (float*)d_out;

  k_fused<<<dim3(NROW / RPB), dim3(TPB), 0, stream>>>(
      q, f, logits, W1q, W1f, b1, W2, b2, Wout, bout, out);
}

// Round 2
// 86.975 us; speedup vs baseline: 1.3672x; 1.3672x over previous
//
#include <hip/hip_runtime.h>
#include <stdint.h>

// Problem constants: B=4, QL=256, CL=512, XD=ED=DIM=128, YD=16
#define Bc   4
#define QLc  256
#define CLc  512
#define Dc   128
#define YDc  16
#define NROW (Bc * QLc)     // 1024 (b,q) rows
#define RPB  2              // rows per block  (round-0 geometry: 2 blocks/CU)
#define TPB  256            // threads per block (4 waves)

// ---------------- Threefry-2x32, 20 rounds (exact JAX semantics) -------------
__device__ __forceinline__ uint32_t rotl32(uint32_t x, int d) {
  return (x << d) | (x >> (32 - d));
}

__device__ __forceinline__ void tf2x32(uint32_t k0, uint32_t k1, uint32_t x0,
                                       uint32_t x1, uint32_t& o0, uint32_t& o1) {
  const uint32_t k2 = k0 ^ k1 ^ 0x1BD11BDAu;
  uint32_t v0 = x0 + k0, v1 = x1 + k1;
  v0 += v1; v1 = rotl32(v1, 13); v1 ^= v0;
  v0 += v1; v1 = rotl32(v1, 15); v1 ^= v0;
  v0 += v1; v1 = rotl32(v1, 26); v1 ^= v0;
  v0 += v1; v1 = rotl32(v1, 6);  v1 ^= v0;
  v0 += k1; v1 += k2 + 1u;
  v0 += v1; v1 = rotl32(v1, 17); v1 ^= v0;
  v0 += v1; v1 = rotl32(v1, 29); v1 ^= v0;
  v0 += v1; v1 = rotl32(v1, 16); v1 ^= v0;
  v0 += v1; v1 = rotl32(v1, 24); v1 ^= v0;
  v0 += k2; v1 += k0 + 2u;
  v0 += v1; v1 = rotl32(v1, 13); v1 ^= v0;
  v0 += v1; v1 = rotl32(v1, 15); v1 ^= v0;
  v0 += v1; v1 = rotl32(v1, 26); v1 ^= v0;
  v0 += v1; v1 = rotl32(v1, 6);  v1 ^= v0;
  v0 += k0; v1 += k1 + 3u;
  v0 += v1; v1 = rotl32(v1, 17); v1 ^= v0;
  v0 += v1; v1 = rotl32(v1, 29); v1 ^= v0;
  v0 += v1; v1 = rotl32(v1, 16); v1 ^= v0;
  v0 += v1; v1 = rotl32(v1, 24); v1 ^= v0;
  v0 += k1; v1 += k2 + 4u;
  v0 += v1; v1 = rotl32(v1, 13); v1 ^= v0;
  v0 += v1; v1 = rotl32(v1, 15); v1 ^= v0;
  v0 += v1; v1 = rotl32(v1, 26); v1 ^= v0;
  v0 += v1; v1 = rotl32(v1, 6);  v1 ^= v0;
  v0 += k2; v1 += k0 + 5u;
  o0 = v0; o1 = v1;
}

// jax.random.key(1) -> data (0,1). Partitionable split: keys[i] = tf(key,(0,i)).
__device__ __forceinline__ void subkeys(uint32_t& ck0, uint32_t& ck1,
                                        uint32_t& ek0, uint32_t& ek1) {
  tf2x32(0u, 1u, 0u, 0u, ck0, ck1);   // kcat
  tf2x32(0u, 1u, 0u, 1u, ek0, ek1);   // keps
}

__device__ __forceinline__ uint32_t rbits(uint32_t k0, uint32_t k1, uint32_t i) {
  uint32_t o0, o1;
  tf2x32(k0, k1, 0u, i, o0, o1);
  return o0 ^ o1;
}

// JAX uniform [0,1): ((bits>>9)|0x3f800000) bitcast - 1.0
__device__ __forceinline__ float bits_to_unit(uint32_t bits) {
  return __uint_as_float((bits >> 9) | 0x3f800000u) - 1.0f;
}

// Giles single-precision erfinv (validated: absmax 0.0 end-to-end)
__device__ __forceinline__ float erfinv_f(float x) {
  float w = -logf((1.0f - x) * (1.0f + x));
  float p;
  if (w < 5.0f) {
    w -= 2.5f;
    p = 2.81022636e-08f;
    p = fmaf(p, w, 3.43273939e-07f);
    p = fmaf(p, w, -3.5233877e-06f);
    p = fmaf(p, w, -4.39150654e-06f);
    p = fmaf(p, w, 0.00021858087f);
    p = fmaf(p, w, -0.00125372503f);
    p = fmaf(p, w, -0.00417768164f);
    p = fmaf(p, w, 0.246640727f);
    p = fmaf(p, w, 1.50140941f);
  } else {
    w = sqrtf(w) - 3.0f;
    p = -0.000200214257f;
    p = fmaf(p, w, 0.000100950558f);
    p = fmaf(p, w, 0.00134934322f);
    p = fmaf(p, w, -0.00367342844f);
    p = fmaf(p, w, 0.00573950773f);
    p = fmaf(p, w, -0.0076224613f);
    p = fmaf(p, w, 0.00943887047f);
    p = fmaf(p, w, 1.00167406f);
    p = fmaf(p, w, 2.83297682f);
  }
  return p * x;
}

// -----------------------------------------------------------------------------
// 512 blocks x 256 threads, 2 (b,q) rows per block — the round-0 geometry.
// 2 independent blocks per CU: under L2 thrash from the harness's concurrent
// 268 MB workspace poison-fill, one block's barrier stall is hidden by the
// other block's waves (the 1-block/CU variant regressed 85->119 us).
// Kept micro-opts vs round 0: shuffle argmax (5 barriers, was 13), float4 LDS
// broadcasts, hoisted data-independent eps threefry, f-gather overlapped with
// the qp matmul, split sh1/sh2 (no WAR barrier), barrier-free sampling tail.
// All fmaf chains keep the exact original op order -> bit-identical (absmax 0).
// -----------------------------------------------------------------------------
__global__ __launch_bounds__(TPB) void k_fused(
    const float* __restrict__ q, const float* __restrict__ f,
    const float* __restrict__ logits, const float* __restrict__ W1q,
    const float* __restrict__ W1f, const float* __restrict__ b1,
    const float* __restrict__ W2, const float* __restrict__ b2,
    const float* __restrict__ Wout, const float* __restrict__ bout,
    float* __restrict__ out) {
  const int tid = threadIdx.x;
  const int r   = tid >> 7;            // 0..1 : which row of the pair
  const int l   = tid & 127;           // 0..127 : lane within row
  const int row = blockIdx.x * RPB + r;
  const int b   = row >> 8;            // QL = 256

  __shared__ __align__(16) float sxq[RPB][Dc];   // staged q rows
  __shared__ __align__(16) float sxf[RPB][Dc];   // staged f[idx] rows
  __shared__ __align__(16) float sh1[RPB][Dc];   // hidden 1
  __shared__ __align__(16) float sh2[RPB][Dc];   // hidden 2
  __shared__ float spart[RPB][4][32];            // split-K partials for Wout
  __shared__ float swv[4];                       // per-wave argmax candidates
  __shared__ int   swi[4];
  __shared__ float seps[RPB * YDc];              // precomputed eps (2 rows x 16)

  // Early-issue the q element this thread owns.
  const float qv = q[row * Dc + l];

  uint32_t ck0, ck1, ek0, ek1;
  subkeys(ck0, ck1, ek0, ek1);       // constant-folds at compile time

  // ---- 0. eps precompute (data-independent, half of wave 0) ----------------
  if (tid < RPB * YDc) {
    const int rr = tid >> 4, y = tid & 15;
    const int orow = blockIdx.x * RPB + rr;
    const uint32_t i = (uint32_t)(orow * YDc + y);   // row-major (b,q,y)
    const uint32_t bits = rbits(ek0, ek1, i);
    const float fl = bits_to_unit(bits);
    const float lo = -0.999999940395355224609375f;   // nextafter(-1,0)
    const float prod = __fmul_rn(fl, 2.0f);
    const float u = fmaxf(lo, __fadd_rn(prod, lo));
    seps[tid] = 1.4142135623730951f * erfinv_f(u);
  }

  sxq[r][l] = qv;

  // ---- 1. gumbel-argmax over this row's 512 logits (first-max ties) --------
  float lgv[4];
#pragma unroll
  for (int j = 0; j < 4; ++j)
    lgv[j] = logits[(uint32_t)(row * CLc + (l + j * 128))];

  float best = -3.4e38f;
  int bi = 1 << 30;
#pragma unroll
  for (int j = 0; j < 4; ++j) {
    const int c = l + j * 128;
    const uint32_t i = (uint32_t)(row * CLc + c);    // row-major (b,q,c)
    const uint32_t bits = rbits(ck0, ck1, i);
    const float fl = bits_to_unit(bits);
    const float u = fmaxf(1.17549435e-38f, fl);      // JAX minval=tiny
    const float g = -logf(-logf(u));                 // gumbel
    const float val = g + lgv[j];
    if (val > best || (val == best && c < bi)) { best = val; bi = c; }
  }
  // intra-wave reduce (total order: larger val, then smaller idx — assoc.)
#pragma unroll
  for (int s = 1; s < 64; s <<= 1) {
    const float ov = __shfl_xor(best, s, 64);
    const int   oi = __shfl_xor(bi, s, 64);
    if (ov > best || (ov == best && oi < bi)) { best = ov; bi = oi; }
  }
  if ((tid & 63) == 0) { swv[tid >> 6] = best; swi[tid >> 6] = bi; }
  __syncthreads();                                   // B1: sxq + candidates

  // resolve per-row winner (row r spans waves 2r, 2r+1)
  int csel;
  {
    const float v0 = swv[2 * r], v1 = swv[2 * r + 1];
    const int   i0 = swi[2 * r], i1 = swi[2 * r + 1];
    csel = (v1 > v0 || (v1 == v0 && i1 < i0)) ? i1 : i0;
  }
  // issue the selected-f-row gather now; qp matmul below hides its latency
  const float fv = f[(b * CLc + csel) * Dc + l];

  // ---- 2. qp = q_row @ W1q (identical fmaf order to reference path) --------
  float acc1 = 0.0f;
  {
    const float4* xp = (const float4*)sxq[r];
#pragma unroll
    for (int h4 = 0; h4 < 32; ++h4) {
      const float4 xv = xp[h4];
      const int h = h4 * 4;
      acc1 = fmaf(xv.x, W1q[(h + 0) * Dc + l], acc1);
      acc1 = fmaf(xv.y, W1q[(h + 1) * Dc + l], acc1);
      acc1 = fmaf(xv.z, W1q[(h + 2) * Dc + l], acc1);
      acc1 = fmaf(xv.w, W1q[(h + 3) * Dc + l], acc1);
    }
  }

  sxf[r][l] = fv;
  __syncthreads();                                   // B2: sxf published

  // ---- 3. fp = f_embed[b, idx] @ W1f ---------------------------------------
  float accf = 0.0f;
  {
    const float4* xp = (const float4*)sxf[r];
#pragma unroll
    for (int h4 = 0; h4 < 32; ++h4) {
      const float4 xv = xp[h4];
      const int h = h4 * 4;
      accf = fmaf(xv.x, W1f[(h + 0) * Dc + l], accf);
      accf = fmaf(xv.y, W1f[(h + 1) * Dc + l], accf);
      accf = fmaf(xv.z, W1f[(h + 2) * Dc + l], accf);
      accf = fmaf(xv.w, W1f[(h + 3) * Dc + l], accf);
    }
  }

  // ---- 4. h1 = relu(qp + fp + b1) ------------------------------------------
  sh1[r][l] = fmaxf(acc1 + accf + b1[l], 0.0f);
  __syncthreads();                                   // B3: sh1 published

  // ---- 5. h2 = relu(h1 @ W2 + b2) ------------------------------------------
  float acc2 = b2[l];
  {
    const float4* xp = (const float4*)sh1[r];
#pragma unroll
    for (int h4 = 0; h4 < 32; ++h4) {
      const float4 xv = xp[h4];
      const int h = h4 * 4;
      acc2 = fmaf(xv.x, W2[(h + 0) * Dc + l], acc2);
      acc2 = fmaf(xv.y, W2[(h + 1) * Dc + l], acc2);
      acc2 = fmaf(xv.z, W2[(h + 2) * Dc + l], acc2);
      acc2 = fmaf(xv.w, W2[(h + 3) * Dc + l], acc2);
    }
  }
  sh2[r][l] = fmaxf(acc2, 0.0f);                     // separate buffer: no WAR
  __syncthreads();                                   // B4: sh2 published

  // ---- 6. out = h2 @ Wout + bout (32 cols/row, split-K by 4 groups of 32) --
  {
    const int k  = tid & 31;
    const int rr = (tid >> 5) & 1;
    const int g  = tid >> 6;                         // 0..3
    float p = 0.0f;
#pragma unroll
    for (int hh = 0; hh < 32; ++hh) {
      const int h = g * 32 + hh;
      p = fmaf(sh2[rr][h], Wout[h * 32 + k], p);
    }
    spart[rr][g][k] = p;
  }
  __syncthreads();                                   // B5: spart published

  // ---- 7. combine + sample, barrier-free tail (wave 0 only) ----------------
  if (tid < 64) {
    const int rr = tid >> 5, k = tid & 31;           // rows 0..1, cols 0..31
    const int orow = blockIdx.x * RPB + rr;
    const float ov = bout[k] + spart[rr][0][k] + spart[rr][1][k] +
                     spart[rr][2][k] + spart[rr][3][k];
    // in-wave exchange: lane with col y grabs col 16+y (the 's' half)
    const float sv_ = __shfl(ov, (tid & 63) + 16, 64);
    if (k < 16) {
      const float mu = ov;
      const float sm = fmaxf(-15.0f, sv_);
      const float sigma = fmaxf(sm, 0.0f) + log1pf(expf(-fabsf(sm)));
      out[orow * YDc + k] = mu + sigma * seps[rr * 16 + k];
    }
  }
}

// -----------------------------------------------------------------------------
extern "C" void kernel_launch(void* const* d_in, const int* in_sizes, int n_in,
                              void* d_out, int out_size, void* d_ws, size_t ws_size,
                              hipStream_t stream) {
  const float* q      = (const float*)d_in[0];
  const float* f      = (const float*)d_in[1];
  const float* logits = (const float*)d_in[2];
  const float* W1q    = (const float*)d_in[3];
  const float* W1f    = (const float*)d_in[4];
  const float* b1     = (const float*)d_in[5];
  const float* W2     = (const float*)d_in[6];
  const float* b2     = (const float*)d_in[7];
  const float* Wout   = (const float*)d_in[8];
  const float* bout   = (const float*)d_in[9];
  float* out = (float*)d_out;

  k_fused<<<dim3(NROW / RPB), dim3(TPB), 0, stream>>>(
      q, f, logits, W1q, W1f, b1, W2, b2, Wout, bout, out);
}